// Round 3
// baseline (2390.847 us; speedup 1.0000x reference)
//
#include <hip/hip_runtime.h>

#define TS 0.01f
constexpr int NX = 32, NU = 16, NF = 512;
constexpr int SEQ = 2048;
constexpr int CH = 32;          // steps per u-chunk / output-flush chunk
constexpr int NT = 512;         // threads per block
// 1 row per block, 512 blocks -> 2 blocks/CU (VGPR<=128), 16 waves/CU

__device__ __forceinline__ float fast_tanh(float y) {
    y = fminf(15.f, fmaxf(-15.f, y));
    float e = __expf(2.f * y);                        // e^{2y}, finite after clamp
    return (e - 1.f) * __builtin_amdgcn_rcpf(e + 1.f);
}

__global__ __launch_bounds__(NT)
__attribute__((amdgpu_waves_per_eu(4, 4)))          // pin VGPR budget to 128: no AGPR spill churn
void fes_kernel(
    const float* __restrict__ x0, const float* __restrict__ ug,
    const float* __restrict__ W1, const float* __restrict__ b1,
    const float* __restrict__ W2, const float* __restrict__ b2,
    float* __restrict__ out)
{
    __shared__ float4 xs4[NX / 4];            // current state (8 float4)
    __shared__ float4 hs4[NF / 4];            // activations (128 float4)
    __shared__ float4 us4[CH][NU / 4];        // u chunk (128 float4)
    __shared__ float4 xo4[CH * NX / 4];       // output staging (256 float4)

    const int tid = threadIdx.x;
    const int row = blockIdx.x;

    // ---- persistent registers --------------------------------------------
    // GEMM1: thread owns feature f = tid; W1 column: 48 VGPRs
    float w1c[48];
#pragma unroll
    for (int k = 0; k < 48; ++k) w1c[k] = W1[k * NF + tid];
    const float b1r = b1[tid];

    // GEMM2: 16 lanes per output j; j = tid>>4, l = tid&15
    // lane's k-slice: k = 4*l + 64*i + c (i<8, c<4) -> 32 VGPRs
    const int j = tid >> 4, l = tid & 15;
    float w2r[32];
#pragma unroll
    for (int i = 0; i < 8; ++i)
#pragma unroll
        for (int c = 0; c < 4; ++c)
            w2r[i * 4 + c] = W2[(4 * l + 64 * i + c) * NX + j];
    const float b2r = b2[j];
    float xreg = x0[row * NX + j];

    const float* ug_row  = ug  + (size_t)row * SEQ * NU;
    float*       out_row = out + (size_t)row * SEQ * NX;

    if (tid < NX) ((float*)xs4)[tid] = x0[row * NX + tid];
    __syncthreads();

    for (int t0 = 0; t0 < SEQ; t0 += CH) {
        // ---- phase 0: flush previous chunk, load u chunk ------------------
        if (t0 > 0 && tid < CH * NX / 4) {            // 256 float4
            const int tc = tid >> 3, jj = tid & 7;
            *(float4*)&out_row[(size_t)(t0 - CH + tc) * NX + jj * 4] = xo4[tid];
        }
        if (tid < CH * NU / 4) {                      // 128 float4
            ((float4*)us4)[tid] = *(const float4*)&ug_row[(size_t)t0 * NU + tid * 4];
        }
        __syncthreads();

        for (int tc = 0; tc < CH; ++tc) {
            // ---- phase 1: h[f] = tanh(W1^T [x;u] + b1) -------------------
            float a0 = 0.f, a1 = 0.f, a2 = 0.f, a3 = 0.f;
#pragma unroll
            for (int kk = 0; kk < 8; ++kk) {
                const float4 xv = xs4[kk];            // wave-uniform -> broadcast
                a0 = fmaf(w1c[4 * kk],     xv.x, a0);
                a1 = fmaf(w1c[4 * kk + 1], xv.y, a1);
                a2 = fmaf(w1c[4 * kk + 2], xv.z, a2);
                a3 = fmaf(w1c[4 * kk + 3], xv.w, a3);
            }
#pragma unroll
            for (int kk = 0; kk < 4; ++kk) {
                const float4 uv = us4[tc][kk];        // wave-uniform -> broadcast
                a0 = fmaf(w1c[32 + 4 * kk], uv.x, a0);
                a1 = fmaf(w1c[33 + 4 * kk], uv.y, a1);
                a2 = fmaf(w1c[34 + 4 * kk], uv.z, a2);
                a3 = fmaf(w1c[35 + 4 * kk], uv.w, a3);
            }
            const float h = fast_tanh(((a0 + a1) + (a2 + a3)) + b1r);
            ((float*)hs4)[tid] = h;
            __syncthreads();

            // ---- phase 2: dx[j] = W2^T h, update state -------------------
            float s0 = 0.f, s1 = 0.f, s2 = 0.f, s3 = 0.f;
#pragma unroll
            for (int i = 0; i < 8; ++i) {
                const float4 hv = hs4[l + 16 * i];    // 2-way conflict max (free), groups broadcast
                s0 = fmaf(hv.x, w2r[4 * i],     s0);
                s1 = fmaf(hv.y, w2r[4 * i + 1], s1);
                s2 = fmaf(hv.z, w2r[4 * i + 2], s2);
                s3 = fmaf(hv.w, w2r[4 * i + 3], s3);
            }
            float s = (s0 + s1) + (s2 + s3);
            s += __shfl_xor(s, 1);
            s += __shfl_xor(s, 2);
            s += __shfl_xor(s, 4);
            s += __shfl_xor(s, 8);                    // all 16 lanes now hold the sum
            const float xn = fmaf(TS, s + b2r, xreg);
            xreg = xn;
            if (l == 0) {
                ((float*)xs4)[j]               = xn;
                ((float*)xo4)[tc * NX + j]     = xn;
            }
            __syncthreads();
        }
    }

    // ---- final flush ------------------------------------------------------
    if (tid < CH * NX / 4) {
        const int tc = tid >> 3, jj = tid & 7;
        *(float4*)&out_row[(size_t)(SEQ - CH + tc) * NX + jj * 4] = xo4[tid];
    }
}

extern "C" void kernel_launch(void* const* d_in, const int* in_sizes, int n_in,
                              void* d_out, int out_size, void* d_ws, size_t ws_size,
                              hipStream_t stream) {
    const float* x0 = (const float*)d_in[0];
    const float* ug = (const float*)d_in[1];
    const float* W1 = (const float*)d_in[2];
    const float* b1 = (const float*)d_in[3];
    const float* W2 = (const float*)d_in[4];
    const float* b2 = (const float*)d_in[5];
    float* out = (float*)d_out;

    dim3 grid(512);    // 1 row per block
    dim3 block(NT);
    fes_kernel<<<grid, block, 0, stream>>>(x0, ug, W1, b1, W2, b2, out);
}

// Round 4
// 2338.583 us; speedup vs baseline: 1.0223x; 1.0223x over previous
//
#include <hip/hip_runtime.h>

constexpr int NX = 32, NU = 16, NF = 512;
constexpr int SEQ = 2048;
constexpr int CH = 32;          // steps per u-chunk
constexpr int NT = 512;         // threads per block; 1 row per block

__device__ __forceinline__ float fast_tanh(float y) {
    y = fminf(15.f, fmaxf(-15.f, y));
    float e = __expf(2.f * y);                        // e^{2y}, finite after clamp
    return (e - 1.f) * __builtin_amdgcn_rcpf(e + 1.f);
}

__global__ __launch_bounds__(NT, 4)   // VGPR budget 128, 2 blocks/CU
void fes_kernel(
    const float* __restrict__ x0, const float* __restrict__ ug,
    const float* __restrict__ W1, const float* __restrict__ b1,
    const float* __restrict__ W2, const float* __restrict__ b2,
    float* __restrict__ out)
{
    __shared__ float4 xs4[NX / 4];            // current state (128 B)
    __shared__ float4 hs4[NF / 4];            // activations (2 KB)
    __shared__ float4 us4[CH][NU / 4];        // u chunk (2 KB)

    const int tid = threadIdx.x;
    const int row = blockIdx.x;
    const int j = tid >> 4, l = tid & 15;     // GEMM2: 16 lanes per output j

    // ---- persistent registers --------------------------------------------
    float w1c[48];                            // W1 column for feature f = tid
#pragma unroll
    for (int k = 0; k < 48; ++k) w1c[k] = W1[k * NF + tid];
    const float b1r = b1[tid];

    float w2r[32];                            // TS-prescaled W2 k-slice
#pragma unroll
    for (int i = 0; i < 8; ++i)
#pragma unroll
        for (int c = 0; c < 4; ++c)
            w2r[i * 4 + c] = 0.01f * W2[(4 * l + 64 * i + c) * NX + j];
    const float s0i = (l == 0) ? 0.01f * b2[j] : 0.f;   // b2 folded into lane 0's acc
    const bool  lz  = (l == 0);

    float xreg = x0[row * NX + j];

    const float* ug_row  = ug  + (size_t)row * SEQ * NU;
    float*       out_row = out + (size_t)row * SEQ * NX;

    if (tid < NX / 4) xs4[tid] = *(const float4*)&x0[row * NX + tid * 4];
    __syncthreads();

    for (int t0 = 0; t0 < SEQ; t0 += CH) {
        // ---- load u chunk (2 KB contiguous) ------------------------------
        if (tid < CH * NU / 4)
            ((float4*)us4)[tid] = *(const float4*)&ug_row[(size_t)t0 * NU + tid * 4];
        __syncthreads();

#pragma unroll 1
        for (int tc = 0; tc < CH; ++tc) {
            // ---- phase 1: h[f] = tanh(W1^T [x;u] + b1) -------------------
            const float4* up = us4[tc];
            float a0 = b1r, a1 = 0.f, a2 = 0.f, a3 = 0.f;
#pragma unroll
            for (int kk = 0; kk < 8; ++kk) {
                const float4 xv = xs4[kk];            // wave-uniform broadcast
                a0 = fmaf(w1c[4 * kk],     xv.x, a0);
                a1 = fmaf(w1c[4 * kk + 1], xv.y, a1);
                a2 = fmaf(w1c[4 * kk + 2], xv.z, a2);
                a3 = fmaf(w1c[4 * kk + 3], xv.w, a3);
            }
#pragma unroll
            for (int kk = 0; kk < 4; ++kk) {
                const float4 uv = up[kk];             // wave-uniform broadcast
                a0 = fmaf(w1c[32 + 4 * kk], uv.x, a0);
                a1 = fmaf(w1c[33 + 4 * kk], uv.y, a1);
                a2 = fmaf(w1c[34 + 4 * kk], uv.z, a2);
                a3 = fmaf(w1c[35 + 4 * kk], uv.w, a3);
            }
            const float h = fast_tanh((a0 + a1) + (a2 + a3));
            ((float*)hs4)[tid] = h;
            __syncthreads();

            // ---- phase 2: x += TS*(W2^T h + b2) (TS pre-folded) ----------
            float s0 = s0i, s1 = 0.f, s2 = 0.f, s3 = 0.f;
#pragma unroll
            for (int i = 0; i < 8; ++i) {
                const float4 hv = hs4[l + 16 * i];    // 2-way max aliasing: free
                s0 = fmaf(hv.x, w2r[4 * i],     s0);
                s1 = fmaf(hv.y, w2r[4 * i + 1], s1);
                s2 = fmaf(hv.z, w2r[4 * i + 2], s2);
                s3 = fmaf(hv.w, w2r[4 * i + 3], s3);
            }
            float s = (s0 + s1) + (s2 + s3);
            s += __shfl_xor(s, 1);
            s += __shfl_xor(s, 2);
            s += __shfl_xor(s, 4);
            s += __shfl_xor(s, 8);
            const float xn = xreg + s;
            xreg = xn;
            if (lz) {
                ((float*)xs4)[j] = xn;
                out_row[(size_t)(t0 + tc) * NX + j] = xn;  // 32 contiguous dwords/block
            }
            __syncthreads();
        }
    }
}

extern "C" void kernel_launch(void* const* d_in, const int* in_sizes, int n_in,
                              void* d_out, int out_size, void* d_ws, size_t ws_size,
                              hipStream_t stream) {
    const float* x0 = (const float*)d_in[0];
    const float* ug = (const float*)d_in[1];
    const float* W1 = (const float*)d_in[2];
    const float* b1 = (const float*)d_in[3];
    const float* W2 = (const float*)d_in[4];
    const float* b2 = (const float*)d_in[5];
    float* out = (float*)d_out;

    fes_kernel<<<dim3(512), dim3(NT), 0, stream>>>(x0, ug, W1, b1, W2, b2, out);
}